// Round 4
// baseline (452.089 us; speedup 1.0000x reference)
//
#include <hip/hip_runtime.h>

#define NN 8192
#define FIN 256
#define FOUT 64
#define NRANK 256   // blocks that do rank+scan before joining the A-stream
#define NBLK 1024
#define NUNITS 1024 // A-stream work units (8 rows each)

typedef int iv4 __attribute__((ext_vector_type(4)));

// K1: Wh = H@W + bW; s = Wh.a1 + a_b; t = Wh.a2; exps + interleaved PP=(e^t, e^.01t).
// Inner loop reads Hs as float4 (uniform ds_read_b128) -> 4x fewer LDS issues.
// Also zeroes the sync/work counters for kA.
__global__ __launch_bounds__(256) void k1_proj(
    const float* __restrict__ H, const float* __restrict__ W,
    const float* __restrict__ bW, const float* __restrict__ aw,
    const float* __restrict__ ab,
    float* __restrict__ Wh, float* __restrict__ s_src, float* __restrict__ t_tar,
    float* __restrict__ E1, float* __restrict__ E2, float* __restrict__ PP,
    unsigned* __restrict__ ctrs)
{
    __shared__ float Hs[16 * FIN];
    int tid = threadIdx.x;
    if (blockIdx.x == 0 && tid < 4) ctrs[tid] = 0u;
    int i0 = blockIdx.x * 16;
    const float4* Hv = (const float4*)(H + (size_t)i0 * FIN);
    float4* Hsv = (float4*)Hs;
    for (int idx = tid; idx < 16 * FIN / 4; idx += 256) Hsv[idx] = Hv[idx];
    __syncthreads();
    int f = tid & 63, sub = tid >> 6;
    float a1f = aw[f], a2f = aw[64 + f];
    float b = bW[f];
    float acc0 = b, acc1 = b, acc2 = b, acc3 = b;
    const float4* h0v = (const float4*)(Hs + (sub     ) * FIN);
    const float4* h1v = (const float4*)(Hs + (sub +  4) * FIN);
    const float4* h2v = (const float4*)(Hs + (sub +  8) * FIN);
    const float4* h3v = (const float4*)(Hs + (sub + 12) * FIN);
    #pragma unroll 4
    for (int k4 = 0; k4 < FIN / 4; ++k4) {
        float4 h0 = h0v[k4], h1 = h1v[k4], h2 = h2v[k4], h3 = h3v[k4];
        float w0 = W[(4 * k4 + 0) * FOUT + f];
        float w1 = W[(4 * k4 + 1) * FOUT + f];
        float w2 = W[(4 * k4 + 2) * FOUT + f];
        float w3 = W[(4 * k4 + 3) * FOUT + f];
        acc0 += h0.x * w0 + h0.y * w1 + h0.z * w2 + h0.w * w3;
        acc1 += h1.x * w0 + h1.y * w1 + h1.z * w2 + h1.w * w3;
        acc2 += h2.x * w0 + h2.y * w1 + h2.z * w2 + h2.w * w3;
        acc3 += h3.x * w0 + h3.y * w1 + h3.z * w2 + h3.w * w3;
    }
    float accs[4] = {acc0, acc1, acc2, acc3};
    #pragma unroll
    for (int q = 0; q < 4; ++q) {
        int i = i0 + sub + 4 * q;
        float a = accs[q];
        Wh[(size_t)i * FOUT + f] = a;
        float v1 = a * a1f, v2 = a * a2f;
        #pragma unroll
        for (int o = 32; o > 0; o >>= 1) {
            v1 += __shfl_xor(v1, o);
            v2 += __shfl_xor(v2, o);
        }
        if (f == 0) {
            float s = v1 + ab[0];
            float t = v2;
            s_src[i] = s; t_tar[i] = t;
            E1[i] = __expf(s); E2[i] = __expf(0.01f * s);
            PP[2 * i]     = __expf(t);
            PP[2 * i + 1] = __expf(0.01f * t);
        }
    }
}

// kA: blocks 0..255 do rank -> (flag barrier) -> chunk tots -> (flag barrier)
// -> prefix/suffix emit, synchronized ONLY among themselves via device-scope
// flag counters (regular launch; at most 256 spinners, all other blocks always
// make progress and retire -> no deadlock at any occupancy). All 1024 blocks
// stream A for denom via dynamic 8-row units; rank blocks join after the scan.
__global__ __launch_bounds__(256, 4) void kA_fused(
    const int* __restrict__ A,
    const float* __restrict__ t_tar, const float* __restrict__ s_src,
    const float* __restrict__ Wh, const float* __restrict__ PP,
    const float* __restrict__ E1, const float* __restrict__ E2,
    int* __restrict__ sorted_idx, int* __restrict__ kidx,
    float* __restrict__ tots1, float* __restrict__ tots2,
    float* __restrict__ pre2, float* __restrict__ suf1,
    float* __restrict__ denom, unsigned* __restrict__ ctrs)
{
    __shared__ float Ts[NN];              // 32 KB; reused as [32][64] stash x3 in scan
    __shared__ float o1p[4][64], o2p[4][64];
    __shared__ float red[4][8][2];
    __shared__ unsigned ucur;
    int tid = threadIdx.x, wv = tid >> 6, lane = tid & 63;
    int b = blockIdx.x;

    if (b < NRANK) {
        // ---------- rank: 32 nodes per block, 8 per wave ----------
        const float4* tv = (const float4*)t_tar;
        float4* Tsv = (float4*)Ts;
        for (int idx = tid; idx < NN / 4; idx += 256) Tsv[idx] = tv[idx];
        __syncthreads();
        int g0 = b * 32 + wv * 8;
        float tj[8], thr[8];
        int rk[8], kc[8];
        #pragma unroll
        for (int q = 0; q < 8; ++q) {
            tj[q] = Ts[g0 + q];
            thr[q] = -s_src[g0 + q];
            rk[q] = 0; kc[q] = 0;
        }
        for (int k = lane; k < NN; k += 64) {
            float tk = Ts[k];
            #pragma unroll
            for (int q = 0; q < 8; ++q) {
                rk[q] += (tk < tj[q] || (tk == tj[q] && k < g0 + q)) ? 1 : 0;
                kc[q] += (tk < thr[q]) ? 1 : 0;
            }
        }
        #pragma unroll
        for (int q = 0; q < 8; ++q) {
            #pragma unroll
            for (int o = 32; o > 0; o >>= 1) {
                rk[q] += __shfl_xor(rk[q], o);
                kc[q] += __shfl_xor(kc[q], o);
            }
        }
        if (lane == 0) {
            #pragma unroll
            for (int q = 0; q < 8; ++q) {
                sorted_idx[rk[q]] = g0 + q;
                kidx[g0 + q] = kc[q];
            }
        }
        __syncthreads();   // drains each wave's global stores (vmcnt(0) before barrier)
        // ---- flag barrier: all rank blocks finished rank ----
        if (tid == 0) {
            __threadfence();
            atomicAdd(&ctrs[0], 1u);
            while (__hip_atomic_load(&ctrs[0], __ATOMIC_ACQUIRE, __HIP_MEMORY_SCOPE_AGENT) < NRANK)
                __builtin_amdgcn_s_sleep(2);
            __threadfence();
        }
        __syncthreads();

        // ---------- chunk b: stash 32 sorted rows + tots ----------
        float* whs = Ts;            // [32][64]
        float* p1s = Ts + 2048;     // [32][64]
        float* p2s = Ts + 4096;     // [32][64]
        int m0 = b * 32;
        float t1p = 0.f, t2p = 0.f;
        #pragma unroll
        for (int q = 0; q < 8; ++q) {
            int m = wv * 8 + q;
            int sj = sorted_idx[m0 + m];
            float wh = Wh[(size_t)sj * 64 + lane];
            float p1 = PP[2 * sj], p2 = PP[2 * sj + 1];
            whs[m * 64 + lane] = wh;
            p1s[m * 64 + lane] = p1;
            p2s[m * 64 + lane] = p2;
            t1p += p1 * wh; t2p += p2 * wh;
        }
        o1p[wv][lane] = t1p; o2p[wv][lane] = t2p;
        __syncthreads();
        if (wv == 0) {
            float t1 = o1p[0][lane] + o1p[1][lane] + o1p[2][lane] + o1p[3][lane];
            float t2 = o2p[0][lane] + o2p[1][lane] + o2p[2][lane] + o2p[3][lane];
            tots1[b * 64 + lane] = t1;
            tots2[b * 64 + lane] = t2;
        }
        __syncthreads();
        // ---- flag barrier: all tots written ----
        if (tid == 0) {
            __threadfence();
            atomicAdd(&ctrs[1], 1u);
            while (__hip_atomic_load(&ctrs[1], __ATOMIC_ACQUIRE, __HIP_MEMORY_SCOPE_AGENT) < NRANK)
                __builtin_amdgcn_s_sleep(2);
            __threadfence();
        }
        __syncthreads();

        // ---------- offsets over other chunks + prefix/suffix emit ----------
        float s1 = 0.f, s2 = 0.f;
        for (int c = wv * 64; c < wv * 64 + 64; ++c) {
            if (c < b) s2 += tots2[c * 64 + lane];
            if (c > b) s1 += tots1[c * 64 + lane];
        }
        o1p[wv][lane] = s1; o2p[wv][lane] = s2;
        __syncthreads();
        if (wv == 0) {
            float o1 = o1p[0][lane] + o1p[1][lane] + o1p[2][lane] + o1p[3][lane];
            float o2 = o2p[0][lane] + o2p[1][lane] + o2p[2][lane] + o2p[3][lane];
            float run2 = o2;
            #pragma unroll 8
            for (int q = 0; q < 32; ++q) {
                pre2[(size_t)(m0 + q) * 64 + lane] = run2;
                run2 += p2s[q * 64 + lane] * whs[q * 64 + lane];
            }
            if (b == NRANK - 1) pre2[(size_t)NN * 64 + lane] = run2;
            float run1 = o1;
            #pragma unroll 8
            for (int q = 31; q >= 0; --q) {
                run1 += p1s[q * 64 + lane] * whs[q * 64 + lane];
                suf1[(size_t)(m0 + q) * 64 + lane] = run1;
            }
            if (b == NRANK - 1) suf1[(size_t)NN * 64 + lane] = 0.f;
        }
        __syncthreads();
    }

    // ---------- A-stream denom: dynamic 8-row units ----------
    for (;;) {
        if (tid == 0) ucur = atomicAdd(&ctrs[2], 1u);
        __syncthreads();
        unsigned u = ucur;
        __syncthreads();
        if (u >= NUNITS) break;
        int i0 = (int)u * 8;
        float e1r[8], accA[8], accB[8];
        #pragma unroll
        for (int r = 0; r < 8; ++r) { e1r[r] = E1[i0 + r]; accA[r] = 0.f; accB[r] = 0.f; }
        const float4* PPv = (const float4*)PP;
        for (int jv = tid; jv < NN / 4; jv += 256) {
            float4 ppA = PPv[2 * jv];
            float4 ppB = PPv[2 * jv + 1];
            #pragma unroll
            for (int r = 0; r < 8; ++r) {
                const iv4 a4 = __builtin_nontemporal_load(
                    (const iv4*)(A + (size_t)(i0 + r) * NN + jv * 4));
                float e1 = e1r[r];
                {
                    bool c = e1 * ppA.x >= 1.0f;
                    float af = (float)a4.x;
                    accA[r] += af * (c ? ppA.x : 0.0f);
                    accB[r] += af * (c ? 0.0f : ppA.y);
                }
                {
                    bool c = e1 * ppA.z >= 1.0f;
                    float af = (float)a4.y;
                    accA[r] += af * (c ? ppA.z : 0.0f);
                    accB[r] += af * (c ? 0.0f : ppA.w);
                }
                {
                    bool c = e1 * ppB.x >= 1.0f;
                    float af = (float)a4.z;
                    accA[r] += af * (c ? ppB.x : 0.0f);
                    accB[r] += af * (c ? 0.0f : ppB.y);
                }
                {
                    bool c = e1 * ppB.z >= 1.0f;
                    float af = (float)a4.w;
                    accA[r] += af * (c ? ppB.z : 0.0f);
                    accB[r] += af * (c ? 0.0f : ppB.w);
                }
            }
        }
        #pragma unroll
        for (int r = 0; r < 8; ++r) {
            #pragma unroll
            for (int o = 32; o > 0; o >>= 1) {
                accA[r] += __shfl_xor(accA[r], o);
                accB[r] += __shfl_xor(accB[r], o);
            }
        }
        if ((tid & 63) == 0) {
            #pragma unroll
            for (int r = 0; r < 8; ++r) { red[wv][r][0] = accA[r]; red[wv][r][1] = accB[r]; }
        }
        __syncthreads();
        if (tid < 8) {
            float sA = red[0][tid][0] + red[1][tid][0] + red[2][tid][0] + red[3][tid][0];
            float sB = red[0][tid][1] + red[1][tid][1] + red[2][tid][1] + red[3][tid][1];
            denom[i0 + tid] = E1[i0 + tid] * sA + E2[i0 + tid] * sB;
        }
        __syncthreads();
    }
}

// K5: out[i][f] = sigmoid( (E1_i*suf1[k_i][f] + E2_i*pre2[k_i][f]) / denom[i] )
__global__ __launch_bounds__(256) void k5_out(
    const float* __restrict__ suf1, const float* __restrict__ pre2,
    const int* __restrict__ kidx, const float* __restrict__ E1,
    const float* __restrict__ E2, const float* __restrict__ denom,
    float* __restrict__ out)
{
    int tid = threadIdx.x;
    int f = tid & 63, sub = tid >> 6;
    int i = blockIdx.x * 4 + sub;
    int k = kidx[i];
    float num = E1[i] * suf1[(size_t)k * 64 + f] + E2[i] * pre2[(size_t)k * 64 + f];
    float x = num / denom[i];
    out[(size_t)i * 64 + f] = 1.0f / (1.0f + __expf(-x));
}

extern "C" void kernel_launch(void* const* d_in, const int* in_sizes, int n_in,
                              void* d_out, int out_size, void* d_ws, size_t ws_size,
                              hipStream_t stream) {
    const float* H  = (const float*)d_in[0];
    const int*   A  = (const int*)d_in[1];
    const float* W  = (const float*)d_in[2];
    const float* bW = (const float*)d_in[3];
    const float* aw = (const float*)d_in[4];
    const float* ab = (const float*)d_in[5];
    float* out = (float*)d_out;

    float* ws    = (float*)d_ws;
    float* Wh    = ws;                    // 524288
    float* s_src = Wh + 524288;           // 8192
    float* t_tar = s_src + 8192;          // 8192
    float* E1    = t_tar + 8192;          // 8192
    float* E2    = E1 + 8192;             // 8192
    float* PP    = E2 + 8192;             // 16384
    float* pre2  = PP + 16384;            // 524352 ((N+1)*64)
    float* suf1  = pre2 + 524352;         // 524352
    float* tots1 = suf1 + 524352;         // 16384 (256*64)
    float* tots2 = tots1 + 16384;         // 16384
    float* denom = tots2 + 16384;         // 8192
    int* sorted_idx = (int*)(denom + 8192);   // 8192 ints
    int* kidx       = sorted_idx + 8192;      // 8192 ints
    unsigned* ctrs  = (unsigned*)(kidx + 8192); // 4 uints

    hipLaunchKernelGGL(k1_proj, dim3(512), dim3(256), 0, stream,
                       H, W, bW, aw, ab, Wh, s_src, t_tar, E1, E2, PP, ctrs);
    hipLaunchKernelGGL(kA_fused, dim3(NBLK), dim3(256), 0, stream,
                       A, t_tar, s_src, Wh, PP, E1, E2,
                       sorted_idx, kidx, tots1, tots2, pre2, suf1, denom, ctrs);
    hipLaunchKernelGGL(k5_out, dim3(2048), dim3(256), 0, stream,
                       suf1, pre2, kidx, E1, E2, denom, out);
}

// Round 5
// 412.674 us; speedup vs baseline: 1.0955x; 1.0955x over previous
//
#include <hip/hip_runtime.h>

#define NN 8192
#define FIN 256
#define FOUT 64
#define NRANK 256   // blocks that also do the rank phase before joining the A-stream
#define NBLK 1024
#define NUNITS 1024 // A-stream work units (8 rows each)

typedef int iv4 __attribute__((ext_vector_type(4)));

// K1: Wh = H@W + bW; s = Wh.a1 + a_b; t = Wh.a2; exps + interleaved PP=(e^t, e^.01t).
// Inner loop reads Hs as float4 (uniform ds_read_b128 broadcast) -> 4x fewer LDS issues.
// Also zeroes the dynamic-work counter for kA.
__global__ __launch_bounds__(256) void k1_proj(
    const float* __restrict__ H, const float* __restrict__ W,
    const float* __restrict__ bW, const float* __restrict__ aw,
    const float* __restrict__ ab,
    float* __restrict__ Wh, float* __restrict__ s_src, float* __restrict__ t_tar,
    float* __restrict__ E1, float* __restrict__ E2, float* __restrict__ PP,
    unsigned* __restrict__ ctrs)
{
    __shared__ float Hs[16 * FIN];
    int tid = threadIdx.x;
    if (blockIdx.x == 0 && tid < 4) ctrs[tid] = 0u;
    int i0 = blockIdx.x * 16;
    const float4* Hv = (const float4*)(H + (size_t)i0 * FIN);
    float4* Hsv = (float4*)Hs;
    for (int idx = tid; idx < 16 * FIN / 4; idx += 256) Hsv[idx] = Hv[idx];
    __syncthreads();
    int f = tid & 63, sub = tid >> 6;
    float a1f = aw[f], a2f = aw[64 + f];
    float b = bW[f];
    float acc0 = b, acc1 = b, acc2 = b, acc3 = b;
    const float4* h0v = (const float4*)(Hs + (sub     ) * FIN);
    const float4* h1v = (const float4*)(Hs + (sub +  4) * FIN);
    const float4* h2v = (const float4*)(Hs + (sub +  8) * FIN);
    const float4* h3v = (const float4*)(Hs + (sub + 12) * FIN);
    #pragma unroll 4
    for (int k4 = 0; k4 < FIN / 4; ++k4) {
        float4 h0 = h0v[k4], h1 = h1v[k4], h2 = h2v[k4], h3 = h3v[k4];
        float w0 = W[(4 * k4 + 0) * FOUT + f];
        float w1 = W[(4 * k4 + 1) * FOUT + f];
        float w2 = W[(4 * k4 + 2) * FOUT + f];
        float w3 = W[(4 * k4 + 3) * FOUT + f];
        acc0 += h0.x * w0 + h0.y * w1 + h0.z * w2 + h0.w * w3;
        acc1 += h1.x * w0 + h1.y * w1 + h1.z * w2 + h1.w * w3;
        acc2 += h2.x * w0 + h2.y * w1 + h2.z * w2 + h2.w * w3;
        acc3 += h3.x * w0 + h3.y * w1 + h3.z * w2 + h3.w * w3;
    }
    float accs[4] = {acc0, acc1, acc2, acc3};
    #pragma unroll
    for (int q = 0; q < 4; ++q) {
        int i = i0 + sub + 4 * q;
        float a = accs[q];
        Wh[(size_t)i * FOUT + f] = a;
        float v1 = a * a1f, v2 = a * a2f;
        #pragma unroll
        for (int o = 32; o > 0; o >>= 1) {
            v1 += __shfl_xor(v1, o);
            v2 += __shfl_xor(v2, o);
        }
        if (f == 0) {
            float s = v1 + ab[0];
            float t = v2;
            s_src[i] = s; t_tar[i] = t;
            E1[i] = __expf(s); E2[i] = __expf(0.01f * s);
            PP[2 * i]     = __expf(t);
            PP[2 * i + 1] = __expf(0.01f * t);
        }
    }
}

// kA: rank (blocks 0..255, 8 nodes/wave) + A-stream denom via dynamic units.
// NO inter-block synchronization: rank outputs (sorted_idx/kidx) and denom are
// only read by LATER kernels (kernel-boundary coherence). Rank work hides under
// the 268 MB A-stream that the other 768 blocks start immediately.
__global__ __launch_bounds__(256, 4) void kA_rank_denom(
    const int* __restrict__ A,
    const float* __restrict__ t_tar, const float* __restrict__ s_src,
    const float* __restrict__ PP,
    const float* __restrict__ E1, const float* __restrict__ E2,
    int* __restrict__ sorted_idx, int* __restrict__ kidx,
    float* __restrict__ denom, unsigned* __restrict__ ctrs)
{
    __shared__ float Ts[NN];
    __shared__ float red[4][8][2];
    __shared__ unsigned ucur;
    int tid = threadIdx.x, wv = tid >> 6, lane = tid & 63;
    int b = blockIdx.x;

    if (b < NRANK) {
        const float4* tv = (const float4*)t_tar;
        float4* Tsv = (float4*)Ts;
        for (int idx = tid; idx < NN / 4; idx += 256) Tsv[idx] = tv[idx];
        __syncthreads();
        int g0 = b * 32 + wv * 8;
        float tj[8], thr[8];
        int rk[8], kc[8];
        #pragma unroll
        for (int q = 0; q < 8; ++q) {
            tj[q] = Ts[g0 + q];
            thr[q] = -s_src[g0 + q];
            rk[q] = 0; kc[q] = 0;
        }
        for (int k = lane; k < NN; k += 64) {
            float tk = Ts[k];
            #pragma unroll
            for (int q = 0; q < 8; ++q) {
                rk[q] += (tk < tj[q] || (tk == tj[q] && k < g0 + q)) ? 1 : 0;
                kc[q] += (tk < thr[q]) ? 1 : 0;
            }
        }
        #pragma unroll
        for (int q = 0; q < 8; ++q) {
            #pragma unroll
            for (int o = 32; o > 0; o >>= 1) {
                rk[q] += __shfl_xor(rk[q], o);
                kc[q] += __shfl_xor(kc[q], o);
            }
        }
        if (lane == 0) {
            #pragma unroll
            for (int q = 0; q < 8; ++q) {
                sorted_idx[rk[q]] = g0 + q;
                kidx[g0 + q] = kc[q];
            }
        }
    }

    // ---------- A-stream denom: dynamic 8-row units ----------
    for (;;) {
        if (tid == 0) ucur = atomicAdd(&ctrs[0], 1u);
        __syncthreads();
        unsigned u = ucur;
        __syncthreads();
        if (u >= NUNITS) break;
        int i0 = (int)u * 8;
        float e1r[8], accA[8], accB[8];
        #pragma unroll
        for (int r = 0; r < 8; ++r) { e1r[r] = E1[i0 + r]; accA[r] = 0.f; accB[r] = 0.f; }
        const float4* PPv = (const float4*)PP;
        for (int jv = tid; jv < NN / 4; jv += 256) {
            float4 ppA = PPv[2 * jv];
            float4 ppB = PPv[2 * jv + 1];
            #pragma unroll
            for (int r = 0; r < 8; ++r) {
                const iv4 a4 = __builtin_nontemporal_load(
                    (const iv4*)(A + (size_t)(i0 + r) * NN + jv * 4));
                float e1 = e1r[r];
                {
                    bool c = e1 * ppA.x >= 1.0f;
                    float af = (float)a4.x;
                    accA[r] += af * (c ? ppA.x : 0.0f);
                    accB[r] += af * (c ? 0.0f : ppA.y);
                }
                {
                    bool c = e1 * ppA.z >= 1.0f;
                    float af = (float)a4.y;
                    accA[r] += af * (c ? ppA.z : 0.0f);
                    accB[r] += af * (c ? 0.0f : ppA.w);
                }
                {
                    bool c = e1 * ppB.x >= 1.0f;
                    float af = (float)a4.z;
                    accA[r] += af * (c ? ppB.x : 0.0f);
                    accB[r] += af * (c ? 0.0f : ppB.y);
                }
                {
                    bool c = e1 * ppB.z >= 1.0f;
                    float af = (float)a4.w;
                    accA[r] += af * (c ? ppB.z : 0.0f);
                    accB[r] += af * (c ? 0.0f : ppB.w);
                }
            }
        }
        #pragma unroll
        for (int r = 0; r < 8; ++r) {
            #pragma unroll
            for (int o = 32; o > 0; o >>= 1) {
                accA[r] += __shfl_xor(accA[r], o);
                accB[r] += __shfl_xor(accB[r], o);
            }
        }
        if ((tid & 63) == 0) {
            #pragma unroll
            for (int r = 0; r < 8; ++r) { red[wv][r][0] = accA[r]; red[wv][r][1] = accB[r]; }
        }
        __syncthreads();
        if (tid < 8) {
            float sA = red[0][tid][0] + red[1][tid][0] + red[2][tid][0] + red[3][tid][0];
            float sB = red[0][tid][1] + red[1][tid][1] + red[2][tid][1] + red[3][tid][1];
            denom[i0 + tid] = E1[i0 + tid] * sA + E2[i0 + tid] * sB;
        }
        __syncthreads();
    }
}

// K3 phase A: per-chunk (32 m's) totals of v1 = P1*Wh and v2 = P2*Wh in sorted order.
__global__ __launch_bounds__(64) void k3a_tots(
    const float* __restrict__ Wh, const float* __restrict__ PP,
    const int* __restrict__ sorted_idx,
    float* __restrict__ tots1, float* __restrict__ tots2)
{
    int c = blockIdx.x, f = threadIdx.x;
    float t1 = 0.f, t2 = 0.f;
    int m0 = c * 32;
    #pragma unroll 8
    for (int m = m0; m < m0 + 32; ++m) {
        int sj = sorted_idx[m];
        float wh = Wh[(size_t)sj * 64 + f];
        t1 += PP[2 * sj]     * wh;
        t2 += PP[2 * sj + 1] * wh;
    }
    tots1[c * 64 + f] = t1; tots2[c * 64 + f] = t2;
}

// K3 phase BC fused: per-block offsets (linear sums over chunk totals) + emit.
__global__ __launch_bounds__(64) void k3bc_emit(
    const float* __restrict__ Wh, const float* __restrict__ PP,
    const int* __restrict__ sorted_idx,
    const float* __restrict__ tots1, const float* __restrict__ tots2,
    float* __restrict__ pre2, float* __restrict__ suf1)
{
    int c = blockIdx.x, f = threadIdx.x;
    float o2 = 0.f;
    #pragma unroll 8
    for (int w = 0; w < c; ++w) o2 += tots2[w * 64 + f];
    float o1 = 0.f;
    #pragma unroll 8
    for (int w = c + 1; w < 256; ++w) o1 += tots1[w * 64 + f];
    int m0 = c * 32;
    float whr[32], p1r[32], p2r[32];
    #pragma unroll
    for (int q = 0; q < 32; ++q) {
        int sj = sorted_idx[m0 + q];
        whr[q] = Wh[(size_t)sj * 64 + f];
        p1r[q] = PP[2 * sj]; p2r[q] = PP[2 * sj + 1];
    }
    float run2 = o2;
    #pragma unroll
    for (int q = 0; q < 32; ++q) {
        pre2[(size_t)(m0 + q) * 64 + f] = run2;
        run2 += p2r[q] * whr[q];
    }
    if (c == 255) pre2[(size_t)NN * 64 + f] = run2;   // full prefix total
    float run1 = o1;
    #pragma unroll
    for (int q = 31; q >= 0; --q) {
        run1 += p1r[q] * whr[q];
        suf1[(size_t)(m0 + q) * 64 + f] = run1;
    }
    if (c == 255) suf1[(size_t)NN * 64 + f] = 0.f;
}

// K5: out[i][f] = sigmoid( (E1_i*suf1[k_i][f] + E2_i*pre2[k_i][f]) / denom[i] )
__global__ __launch_bounds__(256) void k5_out(
    const float* __restrict__ suf1, const float* __restrict__ pre2,
    const int* __restrict__ kidx, const float* __restrict__ E1,
    const float* __restrict__ E2, const float* __restrict__ denom,
    float* __restrict__ out)
{
    int tid = threadIdx.x;
    int f = tid & 63, sub = tid >> 6;
    int i = blockIdx.x * 4 + sub;
    int k = kidx[i];
    float num = E1[i] * suf1[(size_t)k * 64 + f] + E2[i] * pre2[(size_t)k * 64 + f];
    float x = num / denom[i];
    out[(size_t)i * 64 + f] = 1.0f / (1.0f + __expf(-x));
}

extern "C" void kernel_launch(void* const* d_in, const int* in_sizes, int n_in,
                              void* d_out, int out_size, void* d_ws, size_t ws_size,
                              hipStream_t stream) {
    const float* H  = (const float*)d_in[0];
    const int*   A  = (const int*)d_in[1];
    const float* W  = (const float*)d_in[2];
    const float* bW = (const float*)d_in[3];
    const float* aw = (const float*)d_in[4];
    const float* ab = (const float*)d_in[5];
    float* out = (float*)d_out;

    float* ws    = (float*)d_ws;
    float* Wh    = ws;                    // 524288
    float* s_src = Wh + 524288;           // 8192
    float* t_tar = s_src + 8192;          // 8192
    float* E1    = t_tar + 8192;          // 8192
    float* E2    = E1 + 8192;             // 8192
    float* PP    = E2 + 8192;             // 16384
    float* pre2  = PP + 16384;            // 524352 ((N+1)*64)
    float* suf1  = pre2 + 524352;         // 524352
    float* tots1 = suf1 + 524352;         // 16384 (256*64)
    float* tots2 = tots1 + 16384;         // 16384
    float* denom = tots2 + 16384;         // 8192
    int* sorted_idx = (int*)(denom + 8192);   // 8192 ints
    int* kidx       = sorted_idx + 8192;      // 8192 ints
    unsigned* ctrs  = (unsigned*)(kidx + 8192); // 4 uints

    hipLaunchKernelGGL(k1_proj, dim3(512), dim3(256), 0, stream,
                       H, W, bW, aw, ab, Wh, s_src, t_tar, E1, E2, PP, ctrs);
    hipLaunchKernelGGL(kA_rank_denom, dim3(NBLK), dim3(256), 0, stream,
                       A, t_tar, s_src, PP, E1, E2, sorted_idx, kidx, denom, ctrs);
    hipLaunchKernelGGL(k3a_tots, dim3(256), dim3(64), 0, stream,
                       Wh, PP, sorted_idx, tots1, tots2);
    hipLaunchKernelGGL(k3bc_emit, dim3(256), dim3(64), 0, stream,
                       Wh, PP, sorted_idx, tots1, tots2, pre2, suf1);
    hipLaunchKernelGGL(k5_out, dim3(2048), dim3(256), 0, stream,
                       suf1, pre2, kidx, E1, E2, denom, out);
}

// Round 6
// 397.255 us; speedup vs baseline: 1.1380x; 1.0388x over previous
//
#include <hip/hip_runtime.h>

#define NN 8192
#define FIN 256
#define FOUT 64
#define NBLK 1024
#define NGEMM 512    // kB blocks 0..511: GEMM -> Wh
#define NRANK 256    // kB blocks 512..767: rank
#define NUNITS 2048  // A-stream work units (4 rows each)

typedef int iv4 __attribute__((ext_vector_type(4)));

// K0: s/t/E1/E2/PP via the decomposed path: s = H.(W a1) + bW.a1 + ab, t = H.(W a2) + bW.a2.
// Cheap (8 MB H read); lets the full GEMM hide under the A-stream in kB.
__global__ __launch_bounds__(256) void k0_st(
    const float* __restrict__ H, const float* __restrict__ W,
    const float* __restrict__ bW, const float* __restrict__ aw,
    const float* __restrict__ ab,
    float* __restrict__ s_src, float* __restrict__ t_tar,
    float* __restrict__ E1, float* __restrict__ E2, float* __restrict__ PP,
    unsigned* __restrict__ ctrs)
{
    __shared__ float wv1[FIN], wv2[FIN];
    int tid = threadIdx.x;
    if (blockIdx.x == 0 && tid < 4) ctrs[tid] = 0u;
    // wv1[t] = W[t,:].a1 ; wv2[t] = W[t,:].a2   (W is [FIN][FOUT] row-major)
    {
        float acc1 = 0.f, acc2 = 0.f;
        const float4* Wr = (const float4*)(W + (size_t)tid * FOUT);
        const float4* A1 = (const float4*)aw;
        const float4* A2 = (const float4*)(aw + FOUT);
        #pragma unroll
        for (int f4 = 0; f4 < FOUT / 4; ++f4) {
            float4 w = Wr[f4], a1 = A1[f4], a2 = A2[f4];
            acc1 += w.x * a1.x + w.y * a1.y + w.z * a1.z + w.w * a1.w;
            acc2 += w.x * a2.x + w.y * a2.y + w.z * a2.z + w.w * a2.w;
        }
        wv1[tid] = acc1; wv2[tid] = acc2;
    }
    // b1 = bW.a1, b2 = bW.a2 (redundant per thread, trivial)
    float b1 = 0.f, b2 = 0.f;
    {
        const float4* Bv = (const float4*)bW;
        const float4* A1 = (const float4*)aw;
        const float4* A2 = (const float4*)(aw + FOUT);
        #pragma unroll
        for (int f4 = 0; f4 < FOUT / 4; ++f4) {
            float4 w = Bv[f4], a1 = A1[f4], a2 = A2[f4];
            b1 += w.x * a1.x + w.y * a1.y + w.z * a1.z + w.w * a1.w;
            b2 += w.x * a2.x + w.y * a2.y + w.z * a2.z + w.w * a2.w;
        }
    }
    __syncthreads();
    int wv = tid >> 6, lane = tid & 63;
    int i0 = blockIdx.x * 16;
    const float4* wv1v = (const float4*)wv1;
    const float4* wv2v = (const float4*)wv2;
    float4 v1 = wv1v[lane], v2 = wv2v[lane];
    #pragma unroll
    for (int r = 0; r < 4; ++r) {
        int i = i0 + wv * 4 + r;
        float4 h = ((const float4*)(H + (size_t)i * FIN))[lane];
        float p1 = h.x * v1.x + h.y * v1.y + h.z * v1.z + h.w * v1.w;
        float p2 = h.x * v2.x + h.y * v2.y + h.z * v2.z + h.w * v2.w;
        #pragma unroll
        for (int o = 32; o > 0; o >>= 1) {
            p1 += __shfl_xor(p1, o);
            p2 += __shfl_xor(p2, o);
        }
        if (lane == 0) {
            float s = p1 + b1 + ab[0];
            float t = p2 + b2;
            s_src[i] = s; t_tar[i] = t;
            E1[i] = __expf(s); E2[i] = __expf(0.01f * s);
            PP[2 * i]     = __expf(t);
            PP[2 * i + 1] = __expf(0.01f * t);
        }
    }
}

// kB: block roles (no inter-block sync anywhere; GEMM/rank outputs are consumed
// only by LATER kernels -> kernel-boundary coherence, the R3-verified pattern):
//   0..511   : GEMM (16 rows -> Wh), then join A-stream
//   512..767 : rank (32 nodes), then join A-stream
//   768..1023: A-stream immediately
// A-stream: dynamic 4-row units; 2048 units / 1024 blocks -> partial rebalance
// around the ~5us GEMM/rank detour.
__global__ __launch_bounds__(256, 4) void kB_gemm_rank_denom(
    const int* __restrict__ A,
    const float* __restrict__ H, const float* __restrict__ W,
    const float* __restrict__ bW,
    const float* __restrict__ t_tar, const float* __restrict__ s_src,
    const float* __restrict__ PP,
    const float* __restrict__ E1, const float* __restrict__ E2,
    float* __restrict__ Wh,
    int* __restrict__ sorted_idx, int* __restrict__ kidx,
    float* __restrict__ denom, unsigned* __restrict__ ctrs)
{
    __shared__ float Ts[NN];           // 32 KB; GEMM overlays Hs (16 KB) here
    __shared__ float red[4][4][2];
    __shared__ unsigned ucur;
    int tid = threadIdx.x, wv = tid >> 6, lane = tid & 63;
    int b = blockIdx.x;

    if (b < NGEMM) {
        // ---------- GEMM: rows 16b..16b+15 -> Wh (identical math to verified k1) ----------
        float* Hs = Ts;
        int i0 = b * 16;
        const float4* Hv = (const float4*)(H + (size_t)i0 * FIN);
        float4* Hsv = (float4*)Hs;
        for (int idx = tid; idx < 16 * FIN / 4; idx += 256) Hsv[idx] = Hv[idx];
        __syncthreads();
        int f = lane, sub = wv;
        float bb = bW[f];
        float acc0 = bb, acc1 = bb, acc2 = bb, acc3 = bb;
        const float4* h0v = (const float4*)(Hs + (sub     ) * FIN);
        const float4* h1v = (const float4*)(Hs + (sub +  4) * FIN);
        const float4* h2v = (const float4*)(Hs + (sub +  8) * FIN);
        const float4* h3v = (const float4*)(Hs + (sub + 12) * FIN);
        #pragma unroll 4
        for (int k4 = 0; k4 < FIN / 4; ++k4) {
            float4 h0 = h0v[k4], h1 = h1v[k4], h2 = h2v[k4], h3 = h3v[k4];
            float w0 = W[(4 * k4 + 0) * FOUT + f];
            float w1 = W[(4 * k4 + 1) * FOUT + f];
            float w2 = W[(4 * k4 + 2) * FOUT + f];
            float w3 = W[(4 * k4 + 3) * FOUT + f];
            acc0 += h0.x * w0 + h0.y * w1 + h0.z * w2 + h0.w * w3;
            acc1 += h1.x * w0 + h1.y * w1 + h1.z * w2 + h1.w * w3;
            acc2 += h2.x * w0 + h2.y * w1 + h2.z * w2 + h2.w * w3;
            acc3 += h3.x * w0 + h3.y * w1 + h3.z * w2 + h3.w * w3;
        }
        Wh[(size_t)(i0 + sub     ) * FOUT + f] = acc0;
        Wh[(size_t)(i0 + sub +  4) * FOUT + f] = acc1;
        Wh[(size_t)(i0 + sub +  8) * FOUT + f] = acc2;
        Wh[(size_t)(i0 + sub + 12) * FOUT + f] = acc3;
        __syncthreads();   // Ts free for any later reuse
    } else if (b < NGEMM + NRANK) {
        // ---------- rank: 32 nodes, 8 per wave ----------
        const float4* tv = (const float4*)t_tar;
        float4* Tsv = (float4*)Ts;
        for (int idx = tid; idx < NN / 4; idx += 256) Tsv[idx] = tv[idx];
        __syncthreads();
        int g0 = (b - NGEMM) * 32 + wv * 8;
        float tj[8], thr[8];
        int rk[8], kc[8];
        #pragma unroll
        for (int q = 0; q < 8; ++q) {
            tj[q] = Ts[g0 + q];
            thr[q] = -s_src[g0 + q];
            rk[q] = 0; kc[q] = 0;
        }
        for (int k = lane; k < NN; k += 64) {
            float tk = Ts[k];
            #pragma unroll
            for (int q = 0; q < 8; ++q) {
                rk[q] += (tk < tj[q] || (tk == tj[q] && k < g0 + q)) ? 1 : 0;
                kc[q] += (tk < thr[q]) ? 1 : 0;
            }
        }
        #pragma unroll
        for (int q = 0; q < 8; ++q) {
            #pragma unroll
            for (int o = 32; o > 0; o >>= 1) {
                rk[q] += __shfl_xor(rk[q], o);
                kc[q] += __shfl_xor(kc[q], o);
            }
        }
        if (lane == 0) {
            #pragma unroll
            for (int q = 0; q < 8; ++q) {
                sorted_idx[rk[q]] = g0 + q;
                kidx[g0 + q] = kc[q];
            }
        }
        __syncthreads();
    }

    // ---------- A-stream denom: dynamic 4-row units ----------
    for (;;) {
        if (tid == 0) ucur = atomicAdd(&ctrs[0], 1u);
        __syncthreads();
        unsigned u = ucur;
        __syncthreads();
        if (u >= NUNITS) break;
        int i0 = (int)u * 4;
        float e1r[4], accA[4], accB[4];
        #pragma unroll
        for (int r = 0; r < 4; ++r) { e1r[r] = E1[i0 + r]; accA[r] = 0.f; accB[r] = 0.f; }
        const float4* PPv = (const float4*)PP;
        #pragma unroll
        for (int m = 0; m < 8; ++m) {
            int jv = tid + 256 * m;
            float4 ppA = PPv[2 * jv];
            float4 ppB = PPv[2 * jv + 1];
            #pragma unroll
            for (int r = 0; r < 4; ++r) {
                const iv4 a4 = __builtin_nontemporal_load(
                    (const iv4*)(A + (size_t)(i0 + r) * NN + jv * 4));
                float e1 = e1r[r];
                {
                    bool c = e1 * ppA.x >= 1.0f;
                    float af = (float)a4.x;
                    accA[r] += af * (c ? ppA.x : 0.0f);
                    accB[r] += af * (c ? 0.0f : ppA.y);
                }
                {
                    bool c = e1 * ppA.z >= 1.0f;
                    float af = (float)a4.y;
                    accA[r] += af * (c ? ppA.z : 0.0f);
                    accB[r] += af * (c ? 0.0f : ppA.w);
                }
                {
                    bool c = e1 * ppB.x >= 1.0f;
                    float af = (float)a4.z;
                    accA[r] += af * (c ? ppB.x : 0.0f);
                    accB[r] += af * (c ? 0.0f : ppB.y);
                }
                {
                    bool c = e1 * ppB.z >= 1.0f;
                    float af = (float)a4.w;
                    accA[r] += af * (c ? ppB.z : 0.0f);
                    accB[r] += af * (c ? 0.0f : ppB.w);
                }
            }
        }
        #pragma unroll
        for (int r = 0; r < 4; ++r) {
            #pragma unroll
            for (int o = 32; o > 0; o >>= 1) {
                accA[r] += __shfl_xor(accA[r], o);
                accB[r] += __shfl_xor(accB[r], o);
            }
        }
        if ((tid & 63) == 0) {
            #pragma unroll
            for (int r = 0; r < 4; ++r) { red[wv][r][0] = accA[r]; red[wv][r][1] = accB[r]; }
        }
        __syncthreads();
        if (tid < 4) {
            float sA = red[0][tid][0] + red[1][tid][0] + red[2][tid][0] + red[3][tid][0];
            float sB = red[0][tid][1] + red[1][tid][1] + red[2][tid][1] + red[3][tid][1];
            denom[i0 + tid] = E1[i0 + tid] * sA + E2[i0 + tid] * sB;
        }
        __syncthreads();
    }
}

// K3 phase A: per-chunk (32 m's) totals of v1 = P1*Wh and v2 = P2*Wh in sorted order.
__global__ __launch_bounds__(64) void k3a_tots(
    const float* __restrict__ Wh, const float* __restrict__ PP,
    const int* __restrict__ sorted_idx,
    float* __restrict__ tots1, float* __restrict__ tots2)
{
    int c = blockIdx.x, f = threadIdx.x;
    float t1 = 0.f, t2 = 0.f;
    int m0 = c * 32;
    #pragma unroll 8
    for (int m = m0; m < m0 + 32; ++m) {
        int sj = sorted_idx[m];
        float wh = Wh[(size_t)sj * 64 + f];
        t1 += PP[2 * sj]     * wh;
        t2 += PP[2 * sj + 1] * wh;
    }
    tots1[c * 64 + f] = t1; tots2[c * 64 + f] = t2;
}

// K3 phase BC fused: per-block offsets (linear sums over chunk totals) + emit.
__global__ __launch_bounds__(64) void k3bc_emit(
    const float* __restrict__ Wh, const float* __restrict__ PP,
    const int* __restrict__ sorted_idx,
    const float* __restrict__ tots1, const float* __restrict__ tots2,
    float* __restrict__ pre2, float* __restrict__ suf1)
{
    int c = blockIdx.x, f = threadIdx.x;
    float o2 = 0.f;
    #pragma unroll 8
    for (int w = 0; w < c; ++w) o2 += tots2[w * 64 + f];
    float o1 = 0.f;
    #pragma unroll 8
    for (int w = c + 1; w < 256; ++w) o1 += tots1[w * 64 + f];
    int m0 = c * 32;
    float whr[32], p1r[32], p2r[32];
    #pragma unroll
    for (int q = 0; q < 32; ++q) {
        int sj = sorted_idx[m0 + q];
        whr[q] = Wh[(size_t)sj * 64 + f];
        p1r[q] = PP[2 * sj]; p2r[q] = PP[2 * sj + 1];
    }
    float run2 = o2;
    #pragma unroll
    for (int q = 0; q < 32; ++q) {
        pre2[(size_t)(m0 + q) * 64 + f] = run2;
        run2 += p2r[q] * whr[q];
    }
    if (c == 255) pre2[(size_t)NN * 64 + f] = run2;   // full prefix total
    float run1 = o1;
    #pragma unroll
    for (int q = 31; q >= 0; --q) {
        run1 += p1r[q] * whr[q];
        suf1[(size_t)(m0 + q) * 64 + f] = run1;
    }
    if (c == 255) suf1[(size_t)NN * 64 + f] = 0.f;
}

// K5: out[i][f] = sigmoid( (E1_i*suf1[k_i][f] + E2_i*pre2[k_i][f]) / denom[i] )
__global__ __launch_bounds__(256) void k5_out(
    const float* __restrict__ suf1, const float* __restrict__ pre2,
    const int* __restrict__ kidx, const float* __restrict__ E1,
    const float* __restrict__ E2, const float* __restrict__ denom,
    float* __restrict__ out)
{
    int tid = threadIdx.x;
    int f = tid & 63, sub = tid >> 6;
    int i = blockIdx.x * 4 + sub;
    int k = kidx[i];
    float num = E1[i] * suf1[(size_t)k * 64 + f] + E2[i] * pre2[(size_t)k * 64 + f];
    float x = num / denom[i];
    out[(size_t)i * 64 + f] = 1.0f / (1.0f + __expf(-x));
}

extern "C" void kernel_launch(void* const* d_in, const int* in_sizes, int n_in,
                              void* d_out, int out_size, void* d_ws, size_t ws_size,
                              hipStream_t stream) {
    const float* H  = (const float*)d_in[0];
    const int*   A  = (const int*)d_in[1];
    const float* W  = (const float*)d_in[2];
    const float* bW = (const float*)d_in[3];
    const float* aw = (const float*)d_in[4];
    const float* ab = (const float*)d_in[5];
    float* out = (float*)d_out;

    float* ws    = (float*)d_ws;
    float* Wh    = ws;                    // 524288
    float* s_src = Wh + 524288;           // 8192
    float* t_tar = s_src + 8192;          // 8192
    float* E1    = t_tar + 8192;          // 8192
    float* E2    = E1 + 8192;             // 8192
    float* PP    = E2 + 8192;             // 16384
    float* pre2  = PP + 16384;            // 524352 ((N+1)*64)
    float* suf1  = pre2 + 524352;         // 524352
    float* tots1 = suf1 + 524352;         // 16384 (256*64)
    float* tots2 = tots1 + 16384;         // 16384
    float* denom = tots2 + 16384;         // 8192
    int* sorted_idx = (int*)(denom + 8192);   // 8192 ints
    int* kidx       = sorted_idx + 8192;      // 8192 ints
    unsigned* ctrs  = (unsigned*)(kidx + 8192); // 4 uints

    hipLaunchKernelGGL(k0_st, dim3(512), dim3(256), 0, stream,
                       H, W, bW, aw, ab, s_src, t_tar, E1, E2, PP, ctrs);
    hipLaunchKernelGGL(kB_gemm_rank_denom, dim3(NBLK), dim3(256), 0, stream,
                       A, H, W, bW, t_tar, s_src, PP, E1, E2,
                       Wh, sorted_idx, kidx, denom, ctrs);
    hipLaunchKernelGGL(k3a_tots, dim3(256), dim3(64), 0, stream,
                       Wh, PP, sorted_idx, tots1, tots2);
    hipLaunchKernelGGL(k3bc_emit, dim3(256), dim3(64), 0, stream,
                       Wh, PP, sorted_idx, tots1, tots2, pre2, suf1);
    hipLaunchKernelGGL(k5_out, dim3(2048), dim3(256), 0, stream,
                       suf1, pre2, kidx, E1, E2, denom, out);
}